// Round 1
// baseline (59.636 us; speedup 1.0000x reference)
//
#include <hip/hip_runtime.h>

#define NB 64
#define NN 1500
#define NM 100
#define NL 81
#define NBINS 1280
#define KEEP 128

// output geometry
#define DQ 7776000u        // NB*NN*NL delta quads (float4 each)
#define LQ 1944000u        // NB*NN*NL/4 label quads
#define TOTALQ 9720000u
#define DELTA_FLOATS 31104000u

// ---------------- K1: IoU + argmax + masked scores ----------------
__global__ __launch_bounds__(256) void k1_iou(
    const float4* __restrict__ roi, const float4* __restrict__ gt,
    const int* __restrict__ rpos, const int* __restrict__ rneg,
    int* __restrict__ spos, int* __restrict__ sneg, int* __restrict__ best)
{
    __shared__ float4 gtb[NM];
    __shared__ float  gta[NM];
    int b = blockIdx.x / 6;
    int chunk = blockIdx.x % 6;
    int tid = threadIdx.x;
    if (tid < NM) {
        float4 g = gt[b*NM + tid];
        gtb[tid] = g;
        gta[tid] = (g.z - g.x) * (g.w - g.y);   // (gy2-gy1)*(gx2-gx1)
    }
    __syncthreads();
    int n = chunk*256 + tid;
    if (n >= NN) return;
    int idx = b*NN + n;
    float4 r = roi[idx];                        // [y1,x1,y2,x2]
    float by1=r.x, bx1=r.y, by2=r.z, bx2=r.w;
    float barea = (by2-by1)*(bx2-bx1);
    float bestIoU = -1.0f; int bestIdx = 0;
    for (int m = 0; m < NM; ++m) {
        float4 g = gtb[m];
        float xt = fmaxf(bx1, g.y);
        float yt = fmaxf(by1, g.x);
        float xb = fminf(bx2, g.w);
        float yb = fminf(by2, g.z);
        float inter = fmaxf(xb-xt, 0.0f) * fmaxf(yb-yt, 0.0f);
        float uni = (barea + gta[m]) - inter;
        float iou = inter / uni;
        if (iou > bestIoU) { bestIoU = iou; bestIdx = m; }   // strict > keeps first max (argmax semantics)
    }
    best[idx] = bestIdx;
    spos[idx] = (bestIoU > 0.5f) ? rpos[idx] : 0;
    sneg[idx] = (bestIoU < 0.5f && bestIoU > 0.1f) ? rneg[idx] : 0;
}

// ---------------- K2: counting top-128 select + per-row label/deltas ----------------
__global__ __launch_bounds__(256) void k2_select(
    const float4* __restrict__ roi, const float4* __restrict__ gt,
    const int* __restrict__ gtl,
    const int* __restrict__ spos, const int* __restrict__ sneg,
    const int* __restrict__ best,
    int* __restrict__ lbl, float4* __restrict__ d4)
{
    __shared__ int sc[2][NN];            // scores (0 = not a candidate)
    __shared__ unsigned char kp[2][NN];  // keep flags
    __shared__ int hist[NBINS];
    __shared__ int partial[256];
    __shared__ int wcnt[4];
    __shared__ int carry;
    __shared__ int sstar_s, q_s;

    int b = blockIdx.x;
    int tid = threadIdx.x;
    for (int i = tid; i < NN; i += 256) {
        sc[0][i] = spos[b*NN+i];
        sc[1][i] = sneg[b*NN+i];
    }

    for (int m = 0; m < 2; ++m) {
        for (int s = tid; s < NBINS; s += 256) hist[s] = 0;
        if (tid == 0) { sstar_s = 0; q_s = 0; carry = 0; }
        __syncthreads();
        for (int i = tid; i < NN; i += 256) {
            int s = sc[m][i];
            if (s > 0) atomicAdd(&hist[s], 1);
        }
        __syncthreads();
        // per-thread partial over 5 bins, then inclusive suffix scan
        int base = tid*5;
        int p = hist[base]+hist[base+1]+hist[base+2]+hist[base+3]+hist[base+4];
        partial[tid] = p;
        __syncthreads();
        int myp = p;
        for (int off = 1; off < 256; off <<= 1) {
            int v = (tid + off < 256) ? partial[tid+off] : 0;
            __syncthreads();
            partial[tid] += v;
            __syncthreads();
        }
        int running = partial[tid] - myp;   // #scores in bins strictly above my range
        // scan own bins high->low for the unique straddle bin
        for (int s = base+4; s >= base; --s) {
            int c = hist[s];
            // G(s)=running; straddle iff G<128<=G+cnt
            if (s >= 1 && c > 0 && running < KEEP && running + c >= KEEP) {
                sstar_s = s; q_s = KEEP - running;
            }
            running += c;
        }
        __syncthreads();
        int sstar = sstar_s, q = q_s;
        // ordered scan: among score==sstar, keep first q by index
        for (int c0 = 0; c0 < 6; ++c0) {
            int i = c0*256 + tid;
            int s = (i < NN) ? sc[m][i] : 0;
            bool eq = (s > 0) && (s == sstar);
            unsigned long long bal = __ballot(eq);
            int lane = tid & 63, w = tid >> 6;
            if (lane == 0) wcnt[w] = (int)__popcll(bal);
            __syncthreads();
            int pre = carry;
            for (int ww = 0; ww < w; ++ww) pre += wcnt[ww];
            int E = pre + (int)__popcll(bal & ((1ull << lane) - 1ull));
            bool keep = (i < NN) && (s > 0) && (s > sstar || (eq && E < q));
            if (i < NN) kp[m][i] = keep ? 1 : 0;
            __syncthreads();
            if (tid == 0) carry += wcnt[0]+wcnt[1]+wcnt[2]+wcnt[3];
            __syncthreads();
        }
    }
    __syncthreads();
    // finalize per-row label + deltas table
    for (int i = tid; i < NN; i += 256) {
        int idx = b*NN + i;
        bool isp = kp[0][i] != 0;
        bool isn = kp[1][i] != 0;
        int lab = -1;
        float4 dd = make_float4(0.f,0.f,0.f,0.f);
        if (isp) {
            int bi = best[idx];
            lab = gtl[b*NM + bi];
            float4 r = roi[idx];
            float4 g = gt[b*NM + bi];
            float bw = r.w - r.y, bh = r.z - r.x;
            float bcx = r.y + 0.5f*bw, bcy = r.x + 0.5f*bh;
            float gw = g.w - g.y, gh = g.z - g.x;
            float gcx = g.y + 0.5f*gw, gcy = g.x + 0.5f*gh;
            if (bw == 0.0f) bw = 0.001f;
            if (bh == 0.0f) bh = 0.001f;
            float dx = (gw==0.0f) ? 0.0f : (gcx-bcx)/bw;
            float dy = (gh==0.0f) ? 0.0f : (gcy-bcy)/bh;
            float dwv = (gw==0.0f) ? 0.0f : logf(gw/bw);
            float dhv = (gh==0.0f) ? 0.0f : logf(gh/bh);
            dd = make_float4(dy/0.1f, dx/0.1f, dhv/0.2f, dwv/0.2f);
        } else if (isn) {
            lab = 0;   // deltas stay zero (eg==0 path)
        }
        lbl[idx] = lab;
        d4[idx] = dd;
    }
}

// ---------------- K3: full-output writer (the 155.5 MB) ----------------
__global__ __launch_bounds__(256) void k3_write(
    const int* __restrict__ lbl, const float4* __restrict__ d4,
    float* __restrict__ out)
{
    unsigned int stride = gridDim.x * blockDim.x;
    for (unsigned int q = blockIdx.x*blockDim.x + threadIdx.x; q < TOTALQ; q += stride) {
        if (q < DQ) {
            unsigned int bn = q / 81u;
            unsigned int l = q - bn*81u;
            float4 v = make_float4(0.f,0.f,0.f,0.f);
            if ((int)l == lbl[bn]) v = d4[bn];
            reinterpret_cast<float4*>(out)[q] = v;
        } else {
            unsigned int e = (q - DQ) * 4u;
            float4 v;
            unsigned int i0 = e;
            unsigned int bn0 = i0 / 81u;      unsigned int l0 = i0 - bn0*81u;
            unsigned int i1 = e + 1u;
            unsigned int bn1 = i1 / 81u;      unsigned int l1 = i1 - bn1*81u;
            unsigned int i2 = e + 2u;
            unsigned int bn2 = i2 / 81u;      unsigned int l2 = i2 - bn2*81u;
            unsigned int i3 = e + 3u;
            unsigned int bn3 = i3 / 81u;      unsigned int l3 = i3 - bn3*81u;
            v.x = ((int)l0 == lbl[bn0]) ? 1.0f : 0.0f;
            v.y = ((int)l1 == lbl[bn1]) ? 1.0f : 0.0f;
            v.z = ((int)l2 == lbl[bn2]) ? 1.0f : 0.0f;
            v.w = ((int)l3 == lbl[bn3]) ? 1.0f : 0.0f;
            reinterpret_cast<float4*>(out + DELTA_FLOATS)[q - DQ] = v;
        }
    }
}

extern "C" void kernel_launch(void* const* d_in, const int* in_sizes, int n_in,
                              void* d_out, int out_size, void* d_ws, size_t ws_size,
                              hipStream_t stream) {
    const float4* roi = (const float4*)d_in[0];   // [B,N,4] f32
    const float4* gt  = (const float4*)d_in[1];   // [B,M,4] f32
    const int* gtl  = (const int*)d_in[2];        // [B,M]
    const int* rpos = (const int*)d_in[3];        // [B,N]
    const int* rneg = (const int*)d_in[4];        // [B,N]
    float* out = (float*)d_out;

    char* ws = (char*)d_ws;
    int*    spos = (int*)(ws);               // 384000 B
    int*    sneg = (int*)(ws +  384000);     // 384000 B
    int*    best = (int*)(ws +  768000);     // 384000 B
    int*    lbl  = (int*)(ws + 1152000);     // 384000 B
    float4* d4   = (float4*)(ws + 1536000);  // 1536000 B  (total 3.07 MB)

    k1_iou   <<<NB*6, 256, 0, stream>>>(roi, gt, rpos, rneg, spos, sneg, best);
    k2_select<<<NB,   256, 0, stream>>>(roi, gt, gtl, spos, sneg, best, lbl, d4);
    k3_write <<<2048, 256, 0, stream>>>(lbl, d4, out);
}

// Round 2
// 44.496 us; speedup vs baseline: 1.3403x; 1.3403x over previous
//
#include <hip/hip_runtime.h>

#define NB 64
#define NN 1500
#define NM 100
#define NL 81
#define NBINS 1280
#define KEEP 128

#define TOTALQ 9720000u       // total float4 quads in out (38,880,000 floats / 4)
#define DELTA_FLOATS 31104000u
#define IOU_BLOCKS 384
#define GRID_TOTAL 2048

// ---------------- K1: fused IoU (blocks 0..383) + zero-fill (blocks 384..2047) ----------------
__global__ __launch_bounds__(256) void k1_fused(
    const float4* __restrict__ roi, const float4* __restrict__ gt,
    const int* __restrict__ rpos, const int* __restrict__ rneg,
    int* __restrict__ spos, int* __restrict__ sneg, int* __restrict__ best,
    float4* __restrict__ outq)
{
    int blk = blockIdx.x;
    int tid = threadIdx.x;
    if (blk < IOU_BLOCKS) {
        __shared__ float4 gtb[NM];
        __shared__ float  gta[NM];
        int b = blk / 6;
        int chunk = blk % 6;
        if (tid < NM) {
            float4 g = gt[b*NM + tid];
            gtb[tid] = g;
            gta[tid] = (g.z - g.x) * (g.w - g.y);   // (gy2-gy1)*(gx2-gx1)
        }
        __syncthreads();
        int n = chunk*256 + tid;
        if (n >= NN) return;
        int idx = b*NN + n;
        float4 r = roi[idx];                        // [y1,x1,y2,x2]
        float by1=r.x, bx1=r.y, by2=r.z, bx2=r.w;
        float barea = (by2-by1)*(bx2-bx1);
        float bestIoU = -1.0f; int bestIdx = 0;
        for (int m = 0; m < NM; ++m) {
            float4 g = gtb[m];
            float xt = fmaxf(bx1, g.y);
            float yt = fmaxf(by1, g.x);
            float xb = fminf(bx2, g.w);
            float yb = fminf(by2, g.z);
            float inter = fmaxf(xb-xt, 0.0f) * fmaxf(yb-yt, 0.0f);
            float uni = (barea + gta[m]) - inter;
            float iou = inter / uni;
            if (iou > bestIoU) { bestIoU = iou; bestIdx = m; }  // strict > = first-max argmax
        }
        best[idx] = bestIdx;
        spos[idx] = (bestIoU > 0.5f) ? rpos[idx] : 0;
        sneg[idx] = (bestIoU < 0.5f && bestIoU > 0.1f) ? rneg[idx] : 0;
        return;
    }
    // pure zero-fill of the entire output (deltas + labels), fillBuffer-style
    unsigned int t = (unsigned int)(blk - IOU_BLOCKS) * 256u + (unsigned int)tid;
    const unsigned int stride = (GRID_TOTAL - IOU_BLOCKS) * 256u;
    const float4 z = make_float4(0.f, 0.f, 0.f, 0.f);
    for (unsigned int q = t; q < TOTALQ; q += stride) outq[q] = z;
}

// ---------------- K2: counting top-128 select + direct sparse scatter ----------------
__global__ __launch_bounds__(256) void k2_select(
    const float4* __restrict__ roi, const float4* __restrict__ gt,
    const int* __restrict__ gtl,
    const int* __restrict__ spos, const int* __restrict__ sneg,
    const int* __restrict__ best,
    float* __restrict__ out)
{
    __shared__ int sc[2][NN];            // scores (0 = not a candidate)
    __shared__ unsigned char kp[2][NN];  // keep flags
    __shared__ int hist[NBINS];
    __shared__ int partial[256];
    __shared__ int wcnt[4];
    __shared__ int carry;
    __shared__ int sstar_s, q_s;

    int b = blockIdx.x;
    int tid = threadIdx.x;
    for (int i = tid; i < NN; i += 256) {
        sc[0][i] = spos[b*NN+i];
        sc[1][i] = sneg[b*NN+i];
    }

    for (int m = 0; m < 2; ++m) {
        for (int s = tid; s < NBINS; s += 256) hist[s] = 0;
        if (tid == 0) { sstar_s = 0; q_s = 0; carry = 0; }
        __syncthreads();
        for (int i = tid; i < NN; i += 256) {
            int s = sc[m][i];
            if (s > 0) atomicAdd(&hist[s], 1);
        }
        __syncthreads();
        // per-thread partial over 5 bins, then inclusive suffix scan
        int base = tid*5;
        int p = hist[base]+hist[base+1]+hist[base+2]+hist[base+3]+hist[base+4];
        partial[tid] = p;
        __syncthreads();
        int myp = p;
        for (int off = 1; off < 256; off <<= 1) {
            int v = (tid + off < 256) ? partial[tid+off] : 0;
            __syncthreads();
            partial[tid] += v;
            __syncthreads();
        }
        int running = partial[tid] - myp;   // #scores in bins strictly above my range
        for (int s = base+4; s >= base; --s) {
            int c = hist[s];
            if (s >= 1 && c > 0 && running < KEEP && running + c >= KEEP) {
                sstar_s = s; q_s = KEEP - running;   // straddle bin: G<128<=G+cnt
            }
            running += c;
        }
        __syncthreads();
        int sstar = sstar_s, q = q_s;
        // ordered scan: among score==sstar, keep first q by index
        for (int c0 = 0; c0 < 6; ++c0) {
            int i = c0*256 + tid;
            int s = (i < NN) ? sc[m][i] : 0;
            bool eq = (s > 0) && (s == sstar);
            unsigned long long bal = __ballot(eq);
            int lane = tid & 63, w = tid >> 6;
            if (lane == 0) wcnt[w] = (int)__popcll(bal);
            __syncthreads();
            int pre = carry;
            for (int ww = 0; ww < w; ++ww) pre += wcnt[ww];
            int E = pre + (int)__popcll(bal & ((1ull << lane) - 1ull));
            bool keep = (i < NN) && (s > 0) && (s > sstar || (eq && E < q));
            if (i < NN) kp[m][i] = keep ? 1 : 0;
            __syncthreads();
            if (tid == 0) carry += wcnt[0]+wcnt[1]+wcnt[2]+wcnt[3];
            __syncthreads();
        }
    }
    __syncthreads();
    // direct sparse scatter into the (already zero-filled) output
    for (int i = tid; i < NN; i += 256) {
        int idx = b*NN + i;
        bool isp = kp[0][i] != 0;
        bool isn = kp[1][i] != 0;
        if (isp) {
            int bi = best[idx];
            int lab = gtl[b*NM + bi];
            float4 r = roi[idx];
            float4 g = gt[b*NM + bi];
            float bw = r.w - r.y, bh = r.z - r.x;
            float bcx = r.y + 0.5f*bw, bcy = r.x + 0.5f*bh;
            float gw = g.w - g.y, gh = g.z - g.x;
            float gcx = g.y + 0.5f*gw, gcy = g.x + 0.5f*gh;
            if (bw == 0.0f) bw = 0.001f;
            if (bh == 0.0f) bh = 0.001f;
            float dx = (gw==0.0f) ? 0.0f : (gcx-bcx)/bw;
            float dy = (gh==0.0f) ? 0.0f : (gcy-bcy)/bh;
            float dwv = (gw==0.0f) ? 0.0f : logf(gw/bw);
            float dhv = (gh==0.0f) ? 0.0f : logf(gh/bh);
            float4 dd = make_float4(dy/0.1f, dx/0.1f, dhv/0.2f, dwv/0.2f);
            unsigned int slot = (unsigned int)idx * 81u + (unsigned int)lab;
            reinterpret_cast<float4*>(out)[slot] = dd;         // delta quad
            out[DELTA_FLOATS + slot] = 1.0f;                   // one-hot label
        } else if (isn) {
            out[DELTA_FLOATS + (unsigned int)idx * 81u] = 1.0f; // label 0, deltas stay 0
        }
    }
}

extern "C" void kernel_launch(void* const* d_in, const int* in_sizes, int n_in,
                              void* d_out, int out_size, void* d_ws, size_t ws_size,
                              hipStream_t stream) {
    const float4* roi = (const float4*)d_in[0];   // [B,N,4] f32
    const float4* gt  = (const float4*)d_in[1];   // [B,M,4] f32
    const int* gtl  = (const int*)d_in[2];        // [B,M]
    const int* rpos = (const int*)d_in[3];        // [B,N]
    const int* rneg = (const int*)d_in[4];        // [B,N]
    float* out = (float*)d_out;

    char* ws = (char*)d_ws;
    int* spos = (int*)(ws);               // 384000 B
    int* sneg = (int*)(ws +  384000);     // 384000 B
    int* best = (int*)(ws +  768000);     // 384000 B

    k1_fused <<<GRID_TOTAL, 256, 0, stream>>>(roi, gt, rpos, rneg, spos, sneg, best,
                                              (float4*)out);
    k2_select<<<NB, 256, 0, stream>>>(roi, gt, gtl, spos, sneg, best, out);
}